// Round 8
// baseline (155.320 us; speedup 1.0000x reference)
//
#include <hip/hip_runtime.h>
#include <stdint.h>

#define PP     16
#define LRDIM  256
#define DDIM   1024
#define LN_EPS 1e-5f

typedef __attribute__((ext_vector_type(8))) short  short8;
typedef __attribute__((ext_vector_type(4))) float  f32x4;

__device__ __forceinline__ uint32_t bf16_rne(float f) {
    uint32_t u = __builtin_bit_cast(uint32_t, f);
    return (u + 0x7fffu + ((u >> 16) & 1u)) >> 16;
}
__device__ __forceinline__ float bf_lo(uint32_t u) {
    return __builtin_bit_cast(float, u << 16);
}
__device__ __forceinline__ float bf_hi(uint32_t u) {
    return __builtin_bit_cast(float, u & 0xffff0000u);
}

// ---------------------------------------------------------------------------
// K1 fused prep.
// blocks [0,512):  table2b[p][c][j] = bf16(sum_i pe[p][i][j] * bt[c][i]),
//                  8 c-rows/block; bt reads wave-uniform -> scalar loads.
// blocks [512,640): repack W_up [D][LR] f32 -> bf16 MFMA B-frags, KS-MAJOR:
//                  wb[((ks*64)+nfg)*64 + l] = W[nfg*16+(l&15)][ks*32+(l>>4)*8+..7]
// ---------------------------------------------------------------------------
__global__ __launch_bounds__(256) void k_prep(const float* __restrict__ bt,
                                              const float* __restrict__ pe,
                                              const float* __restrict__ W,
                                              unsigned short* __restrict__ t2b,
                                              uint4* __restrict__ wb) {
    if (blockIdx.x < 512) {
        const int p  = blockIdx.x >> 5;          // 0..15
        const int c0 = (blockIdx.x & 31) << 3;   // 0..248
        const int j  = threadIdx.x;
        const float* pep = pe + (size_t)p * LRDIM * LRDIM;
        float a[8];
#pragma unroll
        for (int r = 0; r < 8; ++r) a[r] = 0.f;
#pragma unroll 4
        for (int i = 0; i < LRDIM; ++i) {
            const float v = pep[i * LRDIM + j];          // coalesced across j
#pragma unroll
            for (int r = 0; r < 8; ++r)                   // uniform -> s_loads
                a[r] = fmaf(v, bt[(c0 + r) * LRDIM + i], a[r]);
        }
#pragma unroll
        for (int r = 0; r < 8; ++r)
            t2b[(size_t)((p << 8) + c0 + r) * LRDIM + j] =
                (unsigned short)bf16_rne(a[r]);
    } else {
        const int gt  = (blockIdx.x - 512) * 256 + threadIdx.x;  // 0..32767
        const int l   = gt & 63;
        const int ks  = (gt >> 6) & 7;
        const int nfg = gt >> 9;                                  // 0..63
        const int n   = nfg * 16 + (l & 15);
        const int k   = ks * 32 + (l >> 4) * 8;
        const float* src = W + (size_t)n * LRDIM + k;
        uint32_t r[4];
#pragma unroll
        for (int q = 0; q < 4; ++q) {
            const uint32_t lo = bf16_rne(src[2 * q + 0]);
            const uint32_t hi = bf16_rne(src[2 * q + 1]);
            r[q] = lo | (hi << 16);
        }
        wb[((ks << 6) + nfg) * 64 + l] = make_uint4(r[0], r[1], r[2], r[3]);
    }
}

// ---------------------------------------------------------------------------
// K2: gather-sum. One wave per token; lane owns lr = 4l..4l+3.
// A[tok][256] bf16 out, linear layout.
// ---------------------------------------------------------------------------
__global__ __launch_bounds__(256) void k_gather(const int* __restrict__ ids,
                                                const unsigned short* __restrict__ t2b,
                                                uint2* __restrict__ Aq,
                                                int ntok) {
    const int wid = (blockIdx.x << 2) + (threadIdx.x >> 6);
    const int l   = threadIdx.x & 63;
    if (wid >= ntok) return;

    const int myid = (l < PP) ? ids[(size_t)wid * PP + l] : -1;

    float a0 = 0.f, a1 = 0.f, a2 = 0.f, a3 = 0.f;
#pragma unroll
    for (int p = 0; p < PP; ++p) {
        const int   id  = __shfl(myid, p);
        const float msk = (id >= 0) ? 1.f : 0.f;
        const uint2 v = *(const uint2*)(t2b +
                          ((size_t)((p << 8) + (id & 255)) << 8) + (l << 2));
        a0 = fmaf(msk, bf_lo(v.x), a0);
        a1 = fmaf(msk, bf_hi(v.x), a1);
        a2 = fmaf(msk, bf_lo(v.y), a2);
        a3 = fmaf(msk, bf_hi(v.y), a3);
    }
    uint2 pk;
    pk.x = bf16_rne(a0) | (bf16_rne(a1) << 16);
    pk.y = bf16_rne(a2) | (bf16_rne(a3) << 16);
    Aq[((size_t)wid << 6) + l] = pk;
}

// ---------------------------------------------------------------------------
// K3: MFMA GEMM + fused bias/LN. Barrier-free K-loop, HIGH-OCCUPANCY layout.
// Block = 1024 thr (16 waves), 32 tokens x N=1024; wave w owns cols
// [w*64, w*64+64) -> acc[2][4] = ONLY 32 regs/lane. With B window 32 + af 8 +
// misc, total ~110 <= the 128-reg cap a 1024-thr block mandates -> 4 waves/
// SIMD resident WITHOUT spill (r3/r4/r7 all spilled because acc=64 left no
// room under a 128 cap; r5's no-spill config ran at 2 waves/SIMD = latency-
// bound at ~20cy/instr).
// B: ks-major wb in L2, 2-ks-lookahead register prefetch, all-static indices.
// A: global-direct fragment loads (16 KB tile, L1-resident after first wave).
// ---------------------------------------------------------------------------
__global__ __launch_bounds__(1024) void k_gemm(const unsigned short* __restrict__ A,
                                               const uint4* __restrict__ wb,
                                               const float* __restrict__ b_up,
                                               const float* __restrict__ gamma,
                                               const float* __restrict__ beta,
                                               float* __restrict__ out,
                                               int ntok) {
    __shared__ float ln_s[16][32];
    __shared__ float ln_ss[16][32];

    const int t    = threadIdx.x;
    const int w    = t >> 6;        // wave 0..15
    const int l    = t & 63;
    const int lo4  = l & 15;
    const int hi2  = l >> 4;        // 0..3
    const int tok0 = blockIdx.x << 5;

    f32x4 acc[2][4];
#pragma unroll
    for (int m2 = 0; m2 < 2; ++m2)
#pragma unroll
        for (int nf = 0; nf < 4; ++nf) {
            f32x4 z = {0.f, 0.f, 0.f, 0.f};
            acc[m2][nf] = z;
        }

    const unsigned short* Abase = A + ((size_t)tok0 << 8);
    // wb[((ks<<6) + (w*4+nf))*64 + l]
    const uint4* wpB = wb + ((size_t)(w << 8) + l);
#define BLD(ks_, nf_) wpB[((ks_) << 12) + ((nf_) << 6)]

    uint4 b0[4], b1[4];
#pragma unroll
    for (int j = 0; j < 4; ++j) b0[j] = BLD(0, j);
#pragma unroll
    for (int j = 0; j < 4; ++j) b1[j] = BLD(1, j);

    // one K-step: use BANK, then refill BANK with ks+2 (2-ks lookahead).
#define KSTEP(KS, BANK)                                                       \
    {                                                                         \
        const short8 af0 = *(const short8*)(Abase + (lo4 << 8) +              \
                                            ((KS) << 5) + (hi2 << 3));        \
        const short8 af1 = *(const short8*)(Abase + ((16 + lo4) << 8) +       \
                                            ((KS) << 5) + (hi2 << 3));        \
        _Pragma("unroll")                                                     \
        for (int j = 0; j < 4; ++j) {                                         \
            const short8 bfr = __builtin_bit_cast(short8, BANK[j]);           \
            acc[0][j] = __builtin_amdgcn_mfma_f32_16x16x32_bf16(af0, bfr, acc[0][j], 0, 0, 0); \
            acc[1][j] = __builtin_amdgcn_mfma_f32_16x16x32_bf16(af1, bfr, acc[1][j], 0, 0, 0); \
        }                                                                     \
        if ((KS) < 6) {                                                       \
            _Pragma("unroll")                                                 \
            for (int j = 0; j < 4; ++j) BANK[j] = BLD((KS) + 2, j);           \
        }                                                                     \
    }

    KSTEP(0, b0) KSTEP(1, b1) KSTEP(2, b0) KSTEP(3, b1)
    KSTEP(4, b0) KSTEP(5, b1) KSTEP(6, b0) KSTEP(7, b1)
#undef KSTEP
#undef BLD

    // ---- epilogue: +bias, per-token stats (token slot q = m2*4 + r) ----
    float s_[8], ss_[8];
#pragma unroll
    for (int q = 0; q < 8; ++q) { s_[q] = 0.f; ss_[q] = 0.f; }

#pragma unroll
    for (int nf = 0; nf < 4; ++nf) {
        const int col = (w << 6) + (nf << 4) + lo4;
        const float bu = b_up[col];
#pragma unroll
        for (int m2 = 0; m2 < 2; ++m2) {
            f32x4 v = acc[m2][nf];
            v.x += bu; v.y += bu; v.z += bu; v.w += bu;
            acc[m2][nf] = v;
            const int q0 = m2 * 4;
            s_[q0 + 0] += v.x; ss_[q0 + 0] += v.x * v.x;
            s_[q0 + 1] += v.y; ss_[q0 + 1] += v.y * v.y;
            s_[q0 + 2] += v.z; ss_[q0 + 2] += v.z * v.z;
            s_[q0 + 3] += v.w; ss_[q0 + 3] += v.w * v.w;
        }
    }
#pragma unroll
    for (int off = 1; off < 16; off <<= 1)
#pragma unroll
        for (int q = 0; q < 8; ++q) {
            s_[q]  += __shfl_xor(s_[q], off);
            ss_[q] += __shfl_xor(ss_[q], off);
        }
    if (lo4 == 0) {
#pragma unroll
        for (int q = 0; q < 8; ++q) {
            const int tl = (q >> 2) * 16 + hi2 * 4 + (q & 3);
            ln_s[w][tl]  = s_[q];
            ln_ss[w][tl] = ss_[q];
        }
    }
    __syncthreads();

    float mu_[8], inv_[8];
#pragma unroll
    for (int q = 0; q < 8; ++q) {
        const int tl = (q >> 2) * 16 + hi2 * 4 + (q & 3);
        float S = 0.f, SS = 0.f;
#pragma unroll
        for (int ww = 0; ww < 16; ++ww) { S += ln_s[ww][tl]; SS += ln_ss[ww][tl]; }
        const float mu  = S * (1.f / DDIM);
        const float var = SS * (1.f / DDIM) - mu * mu;
        mu_[q]  = mu;
        inv_[q] = rsqrtf(var + LN_EPS);
    }

    // ---- write out ----
#pragma unroll
    for (int nf = 0; nf < 4; ++nf) {
        const int col = (w << 6) + (nf << 4) + lo4;
        const float g  = gamma[col];
        const float bb = beta[col];
#pragma unroll
        for (int m2 = 0; m2 < 2; ++m2) {
            const f32x4 v = acc[m2][nf];
#pragma unroll
            for (int r = 0; r < 4; ++r) {
                const int q   = m2 * 4 + r;
                const int tl  = m2 * 16 + hi2 * 4 + r;
                const int tok = tok0 + tl;
                if (tok < ntok)
                    out[(size_t)tok * DDIM + col] = (v[r] - mu_[q]) * inv_[q] * g + bb;
            }
        }
    }
}

// ---------------------------------------------------------------------------
extern "C" void kernel_launch(void* const* d_in, const int* in_sizes, int n_in,
                              void* d_out, int out_size, void* d_ws, size_t ws_size,
                              hipStream_t stream) {
    const int*   ids   = (const int*)  d_in[0];
    const float* bt    = (const float*)d_in[1];
    const float* pe    = (const float*)d_in[2];
    const float* W     = (const float*)d_in[3];
    const float* b_up  = (const float*)d_in[4];
    const float* gamma = (const float*)d_in[5];
    const float* beta  = (const float*)d_in[6];
    float* out = (float*)d_out;

    const int ntok = in_sizes[0] / PP;   // B*S = 16384

    char* ws = (char*)d_ws;
    unsigned short* t2b = (unsigned short*)(ws);        // 2 MB
    uint4*          wbb = (uint4*)(ws + (2 << 20));     // 512 KB (ks-major)
    unsigned short* Abf = (unsigned short*)(ws + (3 << 20)); // ntok*256*2 = 8 MB
    uint2*          Aq  = (uint2*)Abf;

    hipLaunchKernelGGL(k_prep, dim3(640), dim3(256), 0, stream, bt, pe, W, t2b, wbb);
    hipLaunchKernelGGL(k_gather, dim3((ntok + 3) / 4), dim3(256), 0, stream,
                       ids, t2b, Aq, ntok);
    hipLaunchKernelGGL(k_gemm, dim3((ntok + 31) / 32), dim3(1024), 0, stream,
                       Abf, wbb, b_up, gamma, beta, out, ntok);
}

// Round 9
// 146.698 us; speedup vs baseline: 1.0588x; 1.0588x over previous
//
#include <hip/hip_runtime.h>
#include <stdint.h>

#define PP     16
#define LRDIM  256
#define DDIM   1024
#define LN_EPS 1e-5f

typedef __attribute__((ext_vector_type(8))) short  short8;
typedef __attribute__((ext_vector_type(4))) float  f32x4;

__device__ __forceinline__ uint32_t bf16_rne(float f) {
    uint32_t u = __builtin_bit_cast(uint32_t, f);
    return (u + 0x7fffu + ((u >> 16) & 1u)) >> 16;
}
__device__ __forceinline__ float bf_lo(uint32_t u) {
    return __builtin_bit_cast(float, u << 16);
}
__device__ __forceinline__ float bf_hi(uint32_t u) {
    return __builtin_bit_cast(float, u & 0xffff0000u);
}

// ---------------------------------------------------------------------------
// K1 fused prep.
// blocks [0,512):  table2b[p][c][j] = bf16(sum_i pe[p][i][j] * bt[c][i]),
//                  8 c-rows/block; bt reads wave-uniform -> scalar loads.
// blocks [512,640): repack W_up [D][LR] f32 -> bf16 MFMA B-frags, KS-MAJOR:
//                  wb[((ks*64)+nfg)*64 + l] = W[nfg*16+(l&15)][ks*32+(l>>4)*8+..7]
// ---------------------------------------------------------------------------
__global__ __launch_bounds__(256) void k_prep(const float* __restrict__ bt,
                                              const float* __restrict__ pe,
                                              const float* __restrict__ W,
                                              unsigned short* __restrict__ t2b,
                                              uint4* __restrict__ wb) {
    if (blockIdx.x < 512) {
        const int p  = blockIdx.x >> 5;          // 0..15
        const int c0 = (blockIdx.x & 31) << 3;   // 0..248
        const int j  = threadIdx.x;
        const float* pep = pe + (size_t)p * LRDIM * LRDIM;
        float a[8];
#pragma unroll
        for (int r = 0; r < 8; ++r) a[r] = 0.f;
#pragma unroll 4
        for (int i = 0; i < LRDIM; ++i) {
            const float v = pep[i * LRDIM + j];          // coalesced across j
#pragma unroll
            for (int r = 0; r < 8; ++r)                   // uniform -> s_loads
                a[r] = fmaf(v, bt[(c0 + r) * LRDIM + i], a[r]);
        }
#pragma unroll
        for (int r = 0; r < 8; ++r)
            t2b[(size_t)((p << 8) + c0 + r) * LRDIM + j] =
                (unsigned short)bf16_rne(a[r]);
    } else {
        const int gt  = (blockIdx.x - 512) * 256 + threadIdx.x;  // 0..32767
        const int l   = gt & 63;
        const int ks  = (gt >> 6) & 7;
        const int nfg = gt >> 9;                                  // 0..63
        const int n   = nfg * 16 + (l & 15);
        const int k   = ks * 32 + (l >> 4) * 8;
        const float* src = W + (size_t)n * LRDIM + k;
        uint32_t r[4];
#pragma unroll
        for (int q = 0; q < 4; ++q) {
            const uint32_t lo = bf16_rne(src[2 * q + 0]);
            const uint32_t hi = bf16_rne(src[2 * q + 1]);
            r[q] = lo | (hi << 16);
        }
        wb[((ks << 6) + nfg) * 64 + l] = make_uint4(r[0], r[1], r[2], r[3]);
    }
}

// ---------------------------------------------------------------------------
// K2: FUSED gather + MFMA GEMM + bias/LN.
// Block = 1024 thr (16 waves), 32 tokens x N=1024.
// __launch_bounds__(1024, 4): explicit 128-reg/wave cap (r8 omitted this ->
// compiler picked a 64-reg/8-wave target and spilled ~250 MB to scratch).
// Budget: acc[2][4]=32 (AGPR) + B-window 32 + af 8 + LN/addr ~30 -> ~105.
//
// Phase 1 (gather): wave w builds tokens {2w, 2w+1}: lane l accumulates
//   lr=4l..4l+3 over 16 masked uint2 gathers from L2-resident t2b, packs to
//   bf16 and ds_writes into the XOR-swizzled A tile (byte ^= (row&7)<<4 —
//   the r2-verified writer/reader pair). Kills the 8 MB A round-trip and
//   the separate k_gather launch.
// Phase 2 (GEMM): barrier-free K-loop; wave w owns cols [w*64,w*64+64):
//   acc[2][4]. B from ks-major wb (L2) with 2-ks-lookahead register window,
//   A-frags from swizzled LDS (4-way conflict = 1.58x, acceptable).
// Phase 3: bias + block-local LN (16-wave reduce) + f32 out.
// ---------------------------------------------------------------------------
__global__ __launch_bounds__(1024, 4) void k_fused(const int* __restrict__ ids,
                                                   const unsigned short* __restrict__ t2b,
                                                   const uint4* __restrict__ wb,
                                                   const float* __restrict__ b_up,
                                                   const float* __restrict__ gamma,
                                                   const float* __restrict__ beta,
                                                   float* __restrict__ out,
                                                   int ntok) {
    __shared__ __align__(16) unsigned char As[32 * 512];   // 16 KB swz A tile
    __shared__ int   ids_s[32 * PP];
    __shared__ float ln_s[16][32];
    __shared__ float ln_ss[16][32];

    const int t    = threadIdx.x;
    const int w    = t >> 6;        // wave 0..15
    const int l    = t & 63;
    const int lo4  = l & 15;
    const int hi2  = l >> 4;        // 0..3
    const int tok0 = blockIdx.x << 5;

    // ---- ids tile ----
    if (t < 32 * PP) {
        const int tok = tok0 + (t >> 4);
        ids_s[t] = (tok < ntok) ? ids[((size_t)tok0 << 4) + t] : -1;
    }
    __syncthreads();

    // ---- phase 1: gather tokens {2w, 2w+1} into swizzled LDS ----
#pragma unroll
    for (int tt = 0; tt < 2; ++tt) {
        const int tl = (w << 1) + tt;
        float a0 = 0.f, a1 = 0.f, a2 = 0.f, a3 = 0.f;
#pragma unroll
        for (int p = 0; p < PP; ++p) {
            const int   id  = ids_s[(tl << 4) + p];       // wave-uniform
            const float msk = (id >= 0) ? 1.f : 0.f;
            const uint2 v = *(const uint2*)(t2b +
                              ((size_t)((p << 8) + (id & 255)) << 8) + (l << 2));
            a0 = fmaf(msk, bf_lo(v.x), a0);
            a1 = fmaf(msk, bf_hi(v.x), a1);
            a2 = fmaf(msk, bf_lo(v.y), a2);
            a3 = fmaf(msk, bf_hi(v.y), a3);
        }
        uint2 pk;
        pk.x = bf16_rne(a0) | (bf16_rne(a1) << 16);
        pk.y = bf16_rne(a2) | (bf16_rne(a3) << 16);
        *(uint2*)(As + (tl << 9) + ((l << 3) ^ ((tl & 7) << 4))) = pk;
    }
    __syncthreads();

    // ---- phase 2: K-loop, acc[m2][nf], wave w owns cols [w*64, w*64+64) ----
    f32x4 acc[2][4];
#pragma unroll
    for (int m2 = 0; m2 < 2; ++m2)
#pragma unroll
        for (int nf = 0; nf < 4; ++nf) {
            f32x4 z = {0.f, 0.f, 0.f, 0.f};
            acc[m2][nf] = z;
        }

    // wb[((ks<<6) + (w*4+nf))*64 + l]
    const uint4* wpB = wb + ((size_t)(w << 8) + l);
#define BLD(ks_, nf_) wpB[((ks_) << 12) + ((nf_) << 6)]

    const int swz = (lo4 & 7) << 4;     // row&7 == lo4&7 for rows lo4, 16+lo4

    uint4 b0[4], b1[4];
#pragma unroll
    for (int j = 0; j < 4; ++j) b0[j] = BLD(0, j);
#pragma unroll
    for (int j = 0; j < 4; ++j) b1[j] = BLD(1, j);

#define KSTEP(KS, BANK)                                                       \
    {                                                                         \
        const short8 af0 = *(const short8*)(As + (lo4 << 9) +                 \
                               ((((KS) << 6) + (hi2 << 4)) ^ swz));           \
        const short8 af1 = *(const short8*)(As + ((16 + lo4) << 9) +          \
                               ((((KS) << 6) + (hi2 << 4)) ^ swz));           \
        _Pragma("unroll")                                                     \
        for (int j = 0; j < 4; ++j) {                                         \
            const short8 bfr = __builtin_bit_cast(short8, BANK[j]);           \
            acc[0][j] = __builtin_amdgcn_mfma_f32_16x16x32_bf16(af0, bfr, acc[0][j], 0, 0, 0); \
            acc[1][j] = __builtin_amdgcn_mfma_f32_16x16x32_bf16(af1, bfr, acc[1][j], 0, 0, 0); \
        }                                                                     \
        if ((KS) < 6) {                                                       \
            _Pragma("unroll")                                                 \
            for (int j = 0; j < 4; ++j) BANK[j] = BLD((KS) + 2, j);           \
        }                                                                     \
    }

    KSTEP(0, b0) KSTEP(1, b1) KSTEP(2, b0) KSTEP(3, b1)
    KSTEP(4, b0) KSTEP(5, b1) KSTEP(6, b0) KSTEP(7, b1)
#undef KSTEP
#undef BLD

    // ---- phase 3: +bias, per-token stats, LN, write ----
    float s_[8], ss_[8];
#pragma unroll
    for (int q = 0; q < 8; ++q) { s_[q] = 0.f; ss_[q] = 0.f; }

#pragma unroll
    for (int nf = 0; nf < 4; ++nf) {
        const int col = (w << 6) + (nf << 4) + lo4;
        const float bu = b_up[col];
#pragma unroll
        for (int m2 = 0; m2 < 2; ++m2) {
            f32x4 v = acc[m2][nf];
            v.x += bu; v.y += bu; v.z += bu; v.w += bu;
            acc[m2][nf] = v;
            const int q0 = m2 * 4;
            s_[q0 + 0] += v.x; ss_[q0 + 0] += v.x * v.x;
            s_[q0 + 1] += v.y; ss_[q0 + 1] += v.y * v.y;
            s_[q0 + 2] += v.z; ss_[q0 + 2] += v.z * v.z;
            s_[q0 + 3] += v.w; ss_[q0 + 3] += v.w * v.w;
        }
    }
#pragma unroll
    for (int off = 1; off < 16; off <<= 1)
#pragma unroll
        for (int q = 0; q < 8; ++q) {
            s_[q]  += __shfl_xor(s_[q], off);
            ss_[q] += __shfl_xor(ss_[q], off);
        }
    if (lo4 == 0) {
#pragma unroll
        for (int q = 0; q < 8; ++q) {
            const int tl = (q >> 2) * 16 + hi2 * 4 + (q & 3);
            ln_s[w][tl]  = s_[q];
            ln_ss[w][tl] = ss_[q];
        }
    }
    __syncthreads();

    float mu_[8], inv_[8];
#pragma unroll
    for (int q = 0; q < 8; ++q) {
        const int tl = (q >> 2) * 16 + hi2 * 4 + (q & 3);
        float S = 0.f, SS = 0.f;
#pragma unroll
        for (int ww = 0; ww < 16; ++ww) { S += ln_s[ww][tl]; SS += ln_ss[ww][tl]; }
        const float mu  = S * (1.f / DDIM);
        const float var = SS * (1.f / DDIM) - mu * mu;
        mu_[q]  = mu;
        inv_[q] = rsqrtf(var + LN_EPS);
    }

#pragma unroll
    for (int nf = 0; nf < 4; ++nf) {
        const int col = (w << 6) + (nf << 4) + lo4;
        const float g  = gamma[col];
        const float bb = beta[col];
#pragma unroll
        for (int m2 = 0; m2 < 2; ++m2) {
            const f32x4 v = acc[m2][nf];
#pragma unroll
            for (int r = 0; r < 4; ++r) {
                const int q   = m2 * 4 + r;
                const int tl  = m2 * 16 + hi2 * 4 + r;
                const int tok = tok0 + tl;
                if (tok < ntok)
                    out[(size_t)tok * DDIM + col] = (v[r] - mu_[q]) * inv_[q] * g + bb;
            }
        }
    }
}

// ---------------------------------------------------------------------------
extern "C" void kernel_launch(void* const* d_in, const int* in_sizes, int n_in,
                              void* d_out, int out_size, void* d_ws, size_t ws_size,
                              hipStream_t stream) {
    const int*   ids   = (const int*)  d_in[0];
    const float* bt    = (const float*)d_in[1];
    const float* pe    = (const float*)d_in[2];
    const float* W     = (const float*)d_in[3];
    const float* b_up  = (const float*)d_in[4];
    const float* gamma = (const float*)d_in[5];
    const float* beta  = (const float*)d_in[6];
    float* out = (float*)d_out;

    const int ntok = in_sizes[0] / PP;   // B*S = 16384

    char* ws = (char*)d_ws;
    unsigned short* t2b = (unsigned short*)(ws);        // 2 MB
    uint4*          wbb = (uint4*)(ws + (2 << 20));     // 512 KB (ks-major)

    hipLaunchKernelGGL(k_prep, dim3(640), dim3(256), 0, stream, bt, pe, W, t2b, wbb);
    hipLaunchKernelGGL(k_fused, dim3((ntok + 31) / 32), dim3(1024), 0, stream,
                       ids, t2b, wbb, b_up, gamma, beta, out, ntok);
}

// Round 11
// 86.890 us; speedup vs baseline: 1.7875x; 1.6883x over previous
//
#include <hip/hip_runtime.h>
#include <stdint.h>

#define PP     16
#define LRDIM  256
#define DDIM   1024
#define LN_EPS 1e-5f

typedef __attribute__((ext_vector_type(8))) short  short8;
typedef __attribute__((ext_vector_type(4))) float  f32x4;

__device__ __forceinline__ uint32_t bf16_rne(float f) {
    uint32_t u = __builtin_bit_cast(uint32_t, f);
    return (u + 0x7fffu + ((u >> 16) & 1u)) >> 16;
}
__device__ __forceinline__ float bf_lo(uint32_t u) {
    return __builtin_bit_cast(float, u << 16);
}
__device__ __forceinline__ float bf_hi(uint32_t u) {
    return __builtin_bit_cast(float, u & 0xffff0000u);
}

// ---------------------------------------------------------------------------
// K1 fused prep.  (unchanged, proven r5-r10)
// blocks [0,512):  table2b[p][c][j] = bf16(sum_i pe[p][i][j] * bt[c][i])
// blocks [512,640): repack W_up -> bf16 MFMA B-frags, KS-MAJOR:
//                  wb[((ks*64)+nfg)*64 + l] = W[nfg*16+(l&15)][ks*32+(l>>4)*8+..7]
// ---------------------------------------------------------------------------
__global__ __launch_bounds__(256) void k_prep(const float* __restrict__ bt,
                                              const float* __restrict__ pe,
                                              const float* __restrict__ W,
                                              unsigned short* __restrict__ t2b,
                                              uint4* __restrict__ wb) {
    if (blockIdx.x < 512) {
        const int p  = blockIdx.x >> 5;          // 0..15
        const int c0 = (blockIdx.x & 31) << 3;   // 0..248
        const int j  = threadIdx.x;
        const float* pep = pe + (size_t)p * LRDIM * LRDIM;
        float a[8];
#pragma unroll
        for (int r = 0; r < 8; ++r) a[r] = 0.f;
#pragma unroll 4
        for (int i = 0; i < LRDIM; ++i) {
            const float v = pep[i * LRDIM + j];          // coalesced across j
#pragma unroll
            for (int r = 0; r < 8; ++r)                   // uniform -> s_loads
                a[r] = fmaf(v, bt[(c0 + r) * LRDIM + i], a[r]);
        }
#pragma unroll
        for (int r = 0; r < 8; ++r)
            t2b[(size_t)((p << 8) + c0 + r) * LRDIM + j] =
                (unsigned short)bf16_rne(a[r]);
    } else {
        const int gt  = (blockIdx.x - 512) * 256 + threadIdx.x;  // 0..32767
        const int l   = gt & 63;
        const int ks  = (gt >> 6) & 7;
        const int nfg = gt >> 9;                                  // 0..63
        const int n   = nfg * 16 + (l & 15);
        const int k   = ks * 32 + (l >> 4) * 8;
        const float* src = W + (size_t)n * LRDIM + k;
        uint32_t r[4];
#pragma unroll
        for (int q = 0; q < 4; ++q) {
            const uint32_t lo = bf16_rne(src[2 * q + 0]);
            const uint32_t hi = bf16_rne(src[2 * q + 1]);
            r[q] = lo | (hi << 16);
        }
        wb[((ks << 6) + nfg) * 64 + l] = make_uint4(r[0], r[1], r[2], r[3]);
    }
}

// ---------------------------------------------------------------------------
// K2: FUSED gather + MFMA GEMM + bias/LN — PROVEN numeric path only.
// Block = 512 thr (8 waves), 32 tokens x N=1024, __launch_bounds__(512,2)
// (only spill-free cap for acc=64; r5 evidence: VGPR 128, WRITE 65.8 MB).
// Phase 1: wave w gathers tokens 4w..4w+3 into XOR-swizzled LDS A tile
//          (r2/r9-verified writer/reader pair).
// Phase 2: barrier-free K-loop, NORMAL operand order mfma(af, bfr) with
//          acc[m2][nf] (r9-verified, absmax 0.03125). B from ks-major wb via
//          2-deep full-K-step register window (bA[8]/bB[8]) — the one new
//          perf lever vs r5's per-use-drain (its 45 us bottleneck).
// Phase 3: r5's epilogue verbatim (scalar stores, 16-lane shuffle reduce).
// ---------------------------------------------------------------------------
__global__ __launch_bounds__(512, 2) void k_fused(const int* __restrict__ ids,
                                                  const unsigned short* __restrict__ t2b,
                                                  const uint4* __restrict__ wb,
                                                  const float* __restrict__ b_up,
                                                  const float* __restrict__ gamma,
                                                  const float* __restrict__ beta,
                                                  float* __restrict__ out,
                                                  int ntok) {
    __shared__ __align__(16) unsigned char As[32 * 512];   // 16 KB swz A tile
    __shared__ int   ids_s[32 * PP];
    __shared__ float ln_s[8][32];
    __shared__ float ln_ss[8][32];

    const int t    = threadIdx.x;
    const int w    = t >> 6;        // wave 0..7
    const int l    = t & 63;
    const int lo4  = l & 15;
    const int hi2  = l >> 4;        // 0..3
    const int tok0 = blockIdx.x << 5;

    // ---- ids tile (512 ids, one per thread) ----
    {
        const int tok = tok0 + (t >> 4);
        ids_s[t] = (tok < ntok) ? ids[((size_t)tok0 << 4) + t] : -1;
    }
    __syncthreads();

    // ---- phase 1: gather tokens 4w..4w+3 into swizzled LDS ----
#pragma unroll
    for (int tt = 0; tt < 4; ++tt) {
        const int tl = (w << 2) + tt;
        float a0 = 0.f, a1 = 0.f, a2 = 0.f, a3 = 0.f;
#pragma unroll
        for (int p = 0; p < PP; ++p) {
            const int   id  = ids_s[(tl << 4) + p];       // wave-uniform
            const float msk = (id >= 0) ? 1.f : 0.f;
            const uint2 v = *(const uint2*)(t2b +
                              ((size_t)((p << 8) + (id & 255)) << 8) + (l << 2));
            a0 = fmaf(msk, bf_lo(v.x), a0);
            a1 = fmaf(msk, bf_hi(v.x), a1);
            a2 = fmaf(msk, bf_lo(v.y), a2);
            a3 = fmaf(msk, bf_hi(v.y), a3);
        }
        uint2 pk;
        pk.x = bf16_rne(a0) | (bf16_rne(a1) << 16);
        pk.y = bf16_rne(a2) | (bf16_rne(a3) << 16);
        *(uint2*)(As + (tl << 9) + ((l << 3) ^ ((tl & 7) << 4))) = pk;
    }
    __syncthreads();

    // ---- phase 2: barrier-free K-loop, normal operand order ----
    f32x4 acc[2][8];
#pragma unroll
    for (int m2 = 0; m2 < 2; ++m2)
#pragma unroll
        for (int nf = 0; nf < 8; ++nf) {
            f32x4 z = {0.f, 0.f, 0.f, 0.f};
            acc[m2][nf] = z;
        }

    // wb[((ks<<6) + (w*8+nf))*64 + l]
    const uint4* wpB = wb + ((size_t)(w << 9) + l);
#define BLD(ks_, nf_) wpB[((ks_) << 12) + ((nf_) << 6)]

    const int swz = (lo4 & 7) << 4;     // row&7 == lo4&7 for rows lo4, 16+lo4

    uint4 bA[8], bB[8];
#pragma unroll
    for (int j = 0; j < 8; ++j) bA[j] = BLD(0, j);
#pragma unroll
    for (int j = 0; j < 8; ++j) bB[j] = BLD(1, j);

    // one K-step: MFMA with BANK, then refill BANK with ks+2 (2-deep).
#define KSTEP(KS, BANK)                                                       \
    {                                                                         \
        const short8 af0 = *(const short8*)(As + (lo4 << 9) +                 \
                               ((((KS) << 6) + (hi2 << 4)) ^ swz));           \
        const short8 af1 = *(const short8*)(As + ((16 + lo4) << 9) +          \
                               ((((KS) << 6) + (hi2 << 4)) ^ swz));           \
        _Pragma("unroll")                                                     \
        for (int j = 0; j < 8; ++j) {                                         \
            const short8 bfr = __builtin_bit_cast(short8, BANK[j]);           \
            acc[0][j] = __builtin_amdgcn_mfma_f32_16x16x32_bf16(af0, bfr, acc[0][j], 0, 0, 0); \
            acc[1][j] = __builtin_amdgcn_mfma_f32_16x16x32_bf16(af1, bfr, acc[1][j], 0, 0, 0); \
        }                                                                     \
        if ((KS) < 6) {                                                       \
            _Pragma("unroll")                                                 \
            for (int j = 0; j < 8; ++j) BANK[j] = BLD((KS) + 2, j);           \
        }                                                                     \
    }

    KSTEP(0, bA) KSTEP(1, bB) KSTEP(2, bA) KSTEP(3, bB)
    KSTEP(4, bA) KSTEP(5, bB) KSTEP(6, bA) KSTEP(7, bB)
#undef KSTEP
#undef BLD

    // ---- phase 3: r5 epilogue verbatim: +bias, stats, LN, scalar stores ----
    float s_[8], ss_[8];
#pragma unroll
    for (int q = 0; q < 8; ++q) { s_[q] = 0.f; ss_[q] = 0.f; }

#pragma unroll
    for (int nf = 0; nf < 8; ++nf) {
        const int col = (w << 7) + (nf << 4) + lo4;
        const float bu = b_up[col];
#pragma unroll
        for (int m2 = 0; m2 < 2; ++m2) {
            f32x4 v = acc[m2][nf];
            v.x += bu; v.y += bu; v.z += bu; v.w += bu;
            acc[m2][nf] = v;
            const int q0 = m2 * 4;
            s_[q0 + 0] += v.x; ss_[q0 + 0] += v.x * v.x;
            s_[q0 + 1] += v.y; ss_[q0 + 1] += v.y * v.y;
            s_[q0 + 2] += v.z; ss_[q0 + 2] += v.z * v.z;
            s_[q0 + 3] += v.w; ss_[q0 + 3] += v.w * v.w;
        }
    }
#pragma unroll
    for (int off = 1; off < 16; off <<= 1)
#pragma unroll
        for (int q = 0; q < 8; ++q) {
            s_[q]  += __shfl_xor(s_[q], off);
            ss_[q] += __shfl_xor(ss_[q], off);
        }
    if (lo4 == 0) {
#pragma unroll
        for (int q = 0; q < 8; ++q) {
            const int tl = (q >> 2) * 16 + hi2 * 4 + (q & 3);
            ln_s[w][tl]  = s_[q];
            ln_ss[w][tl] = ss_[q];
        }
    }
    __syncthreads();

    float mu_[8], inv_[8];
#pragma unroll
    for (int q = 0; q < 8; ++q) {
        const int tl = (q >> 2) * 16 + hi2 * 4 + (q & 3);
        float S = 0.f, SS = 0.f;
#pragma unroll
        for (int ww = 0; ww < 8; ++ww) { S += ln_s[ww][tl]; SS += ln_ss[ww][tl]; }
        const float mu  = S * (1.f / DDIM);
        const float var = SS * (1.f / DDIM) - mu * mu;
        mu_[q]  = mu;
        inv_[q] = rsqrtf(var + LN_EPS);
    }

#pragma unroll
    for (int nf = 0; nf < 8; ++nf) {
        const int col = (w << 7) + (nf << 4) + lo4;
        const float g  = gamma[col];
        const float bb = beta[col];
#pragma unroll
        for (int m2 = 0; m2 < 2; ++m2) {
            const f32x4 v = acc[m2][nf];
#pragma unroll
            for (int r = 0; r < 4; ++r) {
                const int q   = m2 * 4 + r;
                const int tl  = m2 * 16 + hi2 * 4 + r;
                const int tok = tok0 + tl;
                if (tok < ntok)
                    out[(size_t)tok * DDIM + col] = (v[r] - mu_[q]) * inv_[q] * g + bb;
            }
        }
    }
}

// ---------------------------------------------------------------------------
extern "C" void kernel_launch(void* const* d_in, const int* in_sizes, int n_in,
                              void* d_out, int out_size, void* d_ws, size_t ws_size,
                              hipStream_t stream) {
    const int*   ids   = (const int*)  d_in[0];
    const float* bt    = (const float*)d_in[1];
    const float* pe    = (const float*)d_in[2];
    const float* W     = (const float*)d_in[3];
    const float* b_up  = (const float*)d_in[4];
    const float* gamma = (const float*)d_in[5];
    const float* beta  = (const float*)d_in[6];
    float* out = (float*)d_out;

    const int ntok = in_sizes[0] / PP;   // B*S = 16384

    char* ws = (char*)d_ws;
    unsigned short* t2b = (unsigned short*)(ws);        // 2 MB
    uint4*          wbb = (uint4*)(ws + (2 << 20));     // 512 KB (ks-major)

    hipLaunchKernelGGL(k_prep, dim3(640), dim3(256), 0, stream, bt, pe, W, t2b, wbb);
    hipLaunchKernelGGL(k_fused, dim3((ntok + 31) / 32), dim3(512), 0, stream,
                       ids, t2b, wbb, b_up, gamma, beta, out, ntok);
}